// Round 1
// baseline (526.955 us; speedup 1.0000x reference)
//
#include <hip/hip_runtime.h>

// Problem constants (from setup_inputs): src [2,2,160,192,160] f32, flow [2,3,160,192,160] f32
#define BB 2
#define CC 2
#define DD 160
#define HH 192
#define WW 160

__global__ __launch_bounds__(256) void st_warp3d_kernel(
    const float* __restrict__ src,
    const float* __restrict__ flow,
    float* __restrict__ out)
{
    const int N = DD * HH * WW;
    long long idx = (long long)blockIdx.x * blockDim.x + threadIdx.x;
    const long long total = (long long)BB * N;
    if (idx >= total) return;

    const int b = (int)(idx / N);
    const int n = (int)(idx % N);
    const int x = n % WW;
    const int t = n / WW;
    const int y = t % HH;
    const int z = t / HH;

    const float* fl = flow + (long long)b * 3 * N + n;
    const float zc = (float)z + fl[0];
    const float yc = (float)y + fl[(long long)N];
    const float xc = (float)x + fl[2LL * N];

    const float z0f = floorf(zc), y0f = floorf(yc), x0f = floorf(xc);
    const float fz = zc - z0f, fy = yc - y0f, fx = xc - x0f;
    const int z0 = (int)z0f, y0 = (int)y0f, x0 = (int)x0f;

    const float wz[2] = {1.0f - fz, fz};
    const float wy[2] = {1.0f - fy, fy};
    const float wx[2] = {1.0f - fx, fx};

    const float* s0 = src + (long long)b * CC * N;  // channel 0 plane
    float acc0 = 0.0f, acc1 = 0.0f;

#pragma unroll
    for (int dz = 0; dz < 2; ++dz) {
        const int zi = z0 + dz;
        const bool vz = (zi >= 0) && (zi < DD);
#pragma unroll
        for (int dy = 0; dy < 2; ++dy) {
            const int yi = y0 + dy;
            const bool vy = (yi >= 0) && (yi < HH);
            const float wzy = wz[dz] * wy[dy];
#pragma unroll
            for (int dx = 0; dx < 2; ++dx) {
                const int xi = x0 + dx;
                const bool v = vz && vy && (xi >= 0) && (xi < WW);
                if (v) {
                    const float w = wzy * wx[dx];
                    const int lin = (zi * HH + yi) * WW + xi;
                    acc0 += w * s0[lin];
                    acc1 += w * s0[N + lin];
                }
            }
        }
    }

    float* o = out + (long long)b * CC * N + n;
    o[0] = acc0;
    o[(long long)N] = acc1;
}

extern "C" void kernel_launch(void* const* d_in, const int* in_sizes, int n_in,
                              void* d_out, int out_size, void* d_ws, size_t ws_size,
                              hipStream_t stream) {
    const float* src  = (const float*)d_in[0];
    const float* flow = (const float*)d_in[1];
    float* out = (float*)d_out;

    const long long total = (long long)BB * DD * HH * WW;  // 9,830,400 threads
    const int block = 256;
    const long long grid = (total + block - 1) / block;

    st_warp3d_kernel<<<(dim3)(unsigned)grid, block, 0, stream>>>(src, flow, out);
}

// Round 2
// 387.325 us; speedup vs baseline: 1.3605x; 1.3605x over previous
//
#include <hip/hip_runtime.h>

// src [2,2,160,192,160] f32, flow [2,3,160,192,160] f32, out [2,2,160,192,160] f32
#define BB 2
#define CC 2
#define DD 160
#define HH 192
#define WW 160
#define NN (DD * HH * WW)

__global__ __launch_bounds__(256) void st_warp3d_kernel(
    const float* __restrict__ src,
    const float* __restrict__ flow,
    float* __restrict__ out)
{
    const int tid = blockIdx.x * blockDim.x + threadIdx.x;
    const int total = BB * NN;  // 9,830,400
    if (tid >= total) return;

    const int b = (tid >= NN) ? 1 : 0;
    const int n = tid - b * NN;
    const int x = n % WW;
    const int t = n / WW;
    const int y = t % HH;
    const int z = t / HH;

    const float* fl = flow + (size_t)b * 3 * NN + n;
    const float zc = (float)z + fl[0];
    const float yc = (float)y + fl[NN];
    const float xc = (float)x + fl[2 * (size_t)NN];

    const float z0f = floorf(zc), y0f = floorf(yc), x0f = floorf(xc);
    const float fz = zc - z0f, fy = yc - y0f, fx = xc - x0f;
    const int z0 = (int)z0f, y0 = (int)y0f, x0 = (int)x0f;
    const int z1 = z0 + 1, y1 = y0 + 1, x1 = x0 + 1;

    // per-axis weights with out-of-bounds masking folded in (zero-padding)
    const float wz0 = (z0 >= 0 && z0 < DD) ? (1.0f - fz) : 0.0f;
    const float wz1 = (z1 >= 0 && z1 < DD) ? fz : 0.0f;
    const float wy0 = (y0 >= 0 && y0 < HH) ? (1.0f - fy) : 0.0f;
    const float wy1 = (y1 >= 0 && y1 < HH) ? fy : 0.0f;
    const float wx0 = (x0 >= 0 && x0 < WW) ? (1.0f - fx) : 0.0f;
    const float wx1 = (x1 >= 0 && x1 < WW) ? fx : 0.0f;

    // clamped indices (safe addresses; OOB corners have weight 0)
    const int z0c = min(max(z0, 0), DD - 1);
    const int z1c = min(max(z1, 0), DD - 1);
    const int y0c = min(max(y0, 0), HH - 1);
    const int y1c = min(max(y1, 0), HH - 1);
    const int x0c = min(max(x0, 0), WW - 1);
    const int x1c = min(max(x1, 0), WW - 1);

    // 4 row bases
    const int r00 = (z0c * HH + y0c) * WW;
    const int r01 = (z0c * HH + y1c) * WW;
    const int r10 = (z1c * HH + y0c) * WW;
    const int r11 = (z1c * HH + y1c) * WW;

    const int l000 = r00 + x0c, l001 = r00 + x1c;
    const int l010 = r01 + x0c, l011 = r01 + x1c;
    const int l100 = r10 + x0c, l101 = r10 + x1c;
    const int l110 = r11 + x0c, l111 = r11 + x1c;

    const float* s0 = src + (size_t)b * CC * NN;  // channel 0
    const float* s1 = s0 + NN;                    // channel 1

    // issue all 16 gathers up front — independent, one waitcnt
    const float a000 = s0[l000], a001 = s0[l001], a010 = s0[l010], a011 = s0[l011];
    const float a100 = s0[l100], a101 = s0[l101], a110 = s0[l110], a111 = s0[l111];
    const float b000 = s1[l000], b001 = s1[l001], b010 = s1[l010], b011 = s1[l011];
    const float b100 = s1[l100], b101 = s1[l101], b110 = s1[l110], b111 = s1[l111];

    const float w00 = wz0 * wy0, w01 = wz0 * wy1, w10 = wz1 * wy0, w11 = wz1 * wy1;
    const float w000 = w00 * wx0, w001 = w00 * wx1;
    const float w010 = w01 * wx0, w011 = w01 * wx1;
    const float w100 = w10 * wx0, w101 = w10 * wx1;
    const float w110 = w11 * wx0, w111 = w11 * wx1;

    const float acc0 = a000 * w000 + a001 * w001 + a010 * w010 + a011 * w011 +
                       a100 * w100 + a101 * w101 + a110 * w110 + a111 * w111;
    const float acc1 = b000 * w000 + b001 * w001 + b010 * w010 + b011 * w011 +
                       b100 * w100 + b101 * w101 + b110 * w110 + b111 * w111;

    float* o = out + (size_t)b * CC * NN + n;
    o[0] = acc0;
    o[NN] = acc1;
}

extern "C" void kernel_launch(void* const* d_in, const int* in_sizes, int n_in,
                              void* d_out, int out_size, void* d_ws, size_t ws_size,
                              hipStream_t stream) {
    const float* src  = (const float*)d_in[0];
    const float* flow = (const float*)d_in[1];
    float* out = (float*)d_out;

    const int total = BB * NN;
    const int block = 256;
    const int grid = (total + block - 1) / block;

    st_warp3d_kernel<<<grid, block, 0, stream>>>(src, flow, out);
}